// Round 9
// baseline (167.499 us; speedup 1.0000x reference)
//
#include <hip/hip_runtime.h>

namespace {

constexpr int NV = 512;
typedef unsigned long long ull;
constexpr ull INF64 = ~0ULL;
constexpr unsigned WMAX = 0xFFFFFFFFu;

// Edge total order = reference's stable sort: (f32 weight bits, triu index).
// triu index is order-isomorphic to lex (i,j), i<j, so the canonical key
// (w_bits<<32)|(i<<9)|j induces the identical order (w>=0 -> bits monotone).
// Keys globally unique -> unique MST -> Boruvka accepts exactly Kruskal's set.
// This is R3 (measured-best, 97us) with ONLY the merge changed:
//   - 9 barrier'd pointer-jump phases -> barrier-free root walk (validated in R5)
//   - same-address atomicAdd(accTot) storm -> per-wave ballot+popcount
// Scan phase is byte-identical to R3. 13 barriers/round -> 5.
__global__ __launch_bounds__(1024) void boruvka_loss(
    const float* __restrict__ d1, const float* __restrict__ d2,
    float* __restrict__ partial)
{
    const int blk = blockIdx.x;
    const float* __restrict__ Dm = blk ? d2 : d1;
    const float* __restrict__ Do = blk ? d1 : d2;
    const int tid = threadIdx.x;
    const int lane = tid & 63;
    const int wid = tid >> 6;

    __shared__ __align__(16) unsigned comp[NV];   // vertex -> component root
    __shared__ ull best[NV];                      // per-component min out-edge key
    __shared__ unsigned parent[NV];               // hook forest
    __shared__ int waveAcc[16];
    __shared__ float red[16];
    __shared__ int accTot;

    if (tid < NV) { comp[tid] = tid; best[tid] = INF64; }
    if (tid == 0) accTot = 0;

    const int v  = tid >> 1;               // 2 threads per row
    const int c0 = (tid & 1) << 8;         // column half 0 / 256
    const float4* __restrict__ rowp4 =
        reinterpret_cast<const float4*>(Dm + ((size_t)v << 9) + c0);
    const uint4* comp4 = reinterpret_cast<const uint4*>(&comp[c0]);

    float contrib = 0.f;

    __syncthreads();

    for (int round = 0; round < 10; ++round) {
        // ---- scan (R3 body, verbatim): first-wins ascending keeps the
        // canonical smallest column among equal weights within this half-row
        {
            const unsigned cv = comp[v];
            unsigned wmin = WMAX, umin = 0;
            bool any = false;
#pragma unroll 4
            for (int s = 0; s < 64; ++s) {
                float4 w4 = rowp4[s];
                uint4  q4 = comp4[s];
                unsigned wb;
                wb = __float_as_uint(w4.x);
                if ((q4.x != cv) && (!any || wb < wmin)) { wmin = wb; umin = c0 + s*4 + 0; any = true; }
                wb = __float_as_uint(w4.y);
                if ((q4.y != cv) && (wb < wmin || !any)) { wmin = wb; umin = c0 + s*4 + 1; any = true; }
                wb = __float_as_uint(w4.z);
                if ((q4.z != cv) && (wb < wmin || !any)) { wmin = wb; umin = c0 + s*4 + 2; any = true; }
                wb = __float_as_uint(w4.w);
                if ((q4.w != cv) && (wb < wmin || !any)) { wmin = wb; umin = c0 + s*4 + 3; any = true; }
            }
            if (any) {
                unsigned uv = (unsigned)v;
                unsigned lo = (umin < uv) ? ((umin << 9) | uv) : ((uv << 9) | umin);
                atomicMin(&best[cv], ((ull)wmin << 32) | (ull)lo);
            }
        }
        __syncthreads();                           // best final; comp stable

        // ---- hook: component t points across its best edge
        ull he = INF64; unsigned hp = 0, hlo = 0;
        if (tid < NV) {
            unsigned t = (unsigned)tid;
            he = best[t];
            hp = t;
            if (he != INF64) {
                hlo = (unsigned)he & 0x3FFFFu;
                unsigned ci = comp[hlo >> 9], cj = comp[hlo & 511u];
                hp = (ci == t) ? cj : ci;
            }
            parent[t] = hp;
        }
        __syncthreads();

        // ---- break 2-cycles: smaller id of a mutual pair becomes root
        // (unique weights -> every hook cycle is a 2-cycle; race is benign,
        // both interleavings leave exactly the smaller id self-rooted)
        if (tid < NV) {
            unsigned t = (unsigned)tid, p = parent[t];
            if (p != t && parent[p] == t && t < p) parent[t] = t;
        }
        __syncthreads();

        // ---- accept (dedup mutual picks via unique key) + root-walk relabel.
        // No thread writes parent[] in this phase; comp[t] written only by
        // owner and read only by owner here -> race-free.
        bool take = false;
        if (tid < NV && he != INF64) {
            take = !((best[hp] == he) && (hp < (unsigned)tid));
            if (take) {
                float a = __uint_as_float((unsigned)(he >> 32)); // Dm[i][j]
                float b = Do[hlo];                 // (i<<9)|j == i*512+j
                float d = a - b;
                contrib += d * d;
            }
        }
        {
            ull bal = __ballot(take);
            if (lane == 0) waveAcc[wid] = __popcll(bal);
        }
        if (tid < NV) {
            unsigned r = comp[tid];
            while (parent[r] != r) r = parent[r];  // terminates at the 2-cycle root
            comp[tid] = r;
        }
        __syncthreads();

        // ---- reset + termination count
        if (tid < NV) best[tid] = INF64;
        if (tid == 0) {
            int s = 0;
#pragma unroll
            for (int w = 0; w < 16; ++w) s += waveAcc[w];
            accTot += s;
        }
        __syncthreads();
        if (accTot == NV - 1) break;               // uniform post-barrier
    }

    // ---- deterministic reduction: wave butterfly, then fixed-order sum
#pragma unroll
    for (int off = 32; off >= 1; off >>= 1) contrib += __shfl_xor(contrib, off);
    if (lane == 0) red[wid] = contrib;
    __syncthreads();
    if (tid == 0) {
        float s = 0.f;
#pragma unroll
        for (int w = 0; w < 16; ++w) s += red[w];
        partial[blk] = s;
    }
}

__global__ void final_add(const float* __restrict__ partial, float* __restrict__ out) {
    out[0] = partial[0] + partial[1];
}

} // namespace

extern "C" void kernel_launch(void* const* d_in, const int* in_sizes, int n_in,
                              void* d_out, int out_size, void* d_ws, size_t ws_size,
                              hipStream_t stream) {
    const float* d1 = (const float*)d_in[0];
    const float* d2 = (const float*)d_in[1];
    float* out = (float*)d_out;
    float* ws = (float*)d_ws;

    boruvka_loss<<<2, 1024, 0, stream>>>(d1, d2, ws); // writes ws[0], ws[1]
    final_add<<<1, 1, 0, stream>>>(ws, out);
}

// Round 10
// 102.075 us; speedup vs baseline: 1.6409x; 1.6409x over previous
//
#include <hip/hip_runtime.h>

namespace {

constexpr int NV = 512;
typedef unsigned long long ull;
constexpr ull INF64 = ~0ULL;
constexpr unsigned WMAX = 0xFFFFFFFFu;

// Edge total order = reference's stable sort: (f32 weight bits, triu index).
// triu index is order-isomorphic to lex (i,j), i<j, so the canonical key
// (w_bits<<32)|(i<<9)|j induces the identical order (w>=0 -> bits monotone).
// Keys globally unique -> unique MST -> Boruvka accepts exactly Kruskal's set.
//
// Structure = R3 (measured best, 97us) with ONE change: rounds >=1 read a
// per-thread register shortlist (top-4 keys of the half-row, built during
// round 0's full scan) instead of re-reading the 1MB matrix. The smallest
// still-external shortlist entry IS the half-row's min external edge
// (anything smaller is also in the top-4); all-internal -> full rescan.
// Merge phases are R3 verbatim (pointer-jump doubling, NOT root-walk: R8
// measured the root-walk at +70us).
__global__ __launch_bounds__(1024) void boruvka_loss(
    const float* __restrict__ d1, const float* __restrict__ d2,
    float* __restrict__ partial)
{
    const int blk = blockIdx.x;
    const float* __restrict__ Dm = blk ? d2 : d1;
    const float* __restrict__ Do = blk ? d1 : d2;
    const int tid = threadIdx.x;
    const int lane = tid & 63;
    const int wid = tid >> 6;

    __shared__ __align__(16) unsigned comp[NV];   // vertex -> component root
    __shared__ ull best[NV];                      // per-component min out-edge key
    __shared__ unsigned parent[NV];               // hook forest
    __shared__ float red[16];
    __shared__ int accTot;

    if (tid < NV) comp[tid] = tid;
    if (tid == 0) accTot = 0;

    const int v  = tid >> 1;               // 2 threads per row
    const int c0 = (tid & 1) << 8;         // column half 0 / 256
    const float4* __restrict__ rowp4 =
        reinterpret_cast<const float4*>(Dm + ((size_t)v << 9) + c0);
    const uint4* comp4 = reinterpret_cast<const uint4*>(&comp[c0]);

    // register shortlist: 4 smallest (w_bits<<32)|col keys of this half-row.
    // Sorted ascending. The diagonal (w=0, col==v) lands in s0 for the half
    // that contains it and is permanently "internal" -> skipped by the pick.
    ull s0 = INF64, s1 = INF64, s2 = INF64, s3 = INF64;

    float contrib = 0.f;

    __syncthreads();

    for (int round = 0; round < 10; ++round) {
        if (tid < NV) best[tid] = INF64;
        __syncthreads();

        const unsigned cv = comp[v];

        if (round == 0) {
            // ---- full scan + shortlist build (sorted insert, strict <)
#pragma unroll 4
            for (int s = 0; s < 64; ++s) {
                float4 w4 = rowp4[s];
                unsigned u0 = (unsigned)(c0 + s * 4);
                ull cand;
#pragma unroll
                for (int k = 0; k < 4; ++k) {
                    float wk = k == 0 ? w4.x : k == 1 ? w4.y : k == 2 ? w4.z : w4.w;
                    cand = ((ull)__float_as_uint(wk) << 32) | (ull)(u0 + k);
                    if (cand < s3) {
                        if (cand < s1) {
                            if (cand < s0) { s3 = s2; s2 = s1; s1 = s0; s0 = cand; }
                            else           { s3 = s2; s2 = s1; s1 = cand; }
                        } else {
                            if (cand < s2) { s3 = s2; s2 = cand; }
                            else           { s3 = cand; }
                        }
                    }
                }
            }
        }

        // ---- pick: first still-external shortlist entry = half-row min ext
        {
            ull pick = INF64;
            unsigned c;
            c = (unsigned)s0 & 511u;
            if (comp[c] != cv) pick = s0;
            else {
                c = (unsigned)s1 & 511u;
                if (comp[c] != cv) pick = s1;
                else {
                    c = (unsigned)s2 & 511u;
                    if (comp[c] != cv) pick = s2;
                    else {
                        c = (unsigned)s3 & 511u;
                        if (comp[c] != cv) pick = s3;
                    }
                }
            }
            if (pick != INF64) {
                unsigned u  = (unsigned)pick & 511u;
                unsigned wv = (unsigned)(pick >> 32);
                unsigned uv = (unsigned)v;
                unsigned lo = (u < uv) ? ((u << 9) | uv) : ((uv << 9) | u);
                atomicMin(&best[cv], ((ull)wv << 32) | (ull)lo);
            } else if (round > 0) {
                // ---- rare: all 4 absorbed -> full masked rescan (R3 body)
                unsigned wmin = WMAX, umin = 0;
                bool any = false;
#pragma unroll 4
                for (int s = 0; s < 64; ++s) {
                    float4 w4 = rowp4[s];
                    uint4  q4 = comp4[s];
                    unsigned wb;
                    wb = __float_as_uint(w4.x);
                    if ((q4.x != cv) && (!any || wb < wmin)) { wmin = wb; umin = c0 + s*4 + 0; any = true; }
                    wb = __float_as_uint(w4.y);
                    if ((q4.y != cv) && (wb < wmin || !any)) { wmin = wb; umin = c0 + s*4 + 1; any = true; }
                    wb = __float_as_uint(w4.z);
                    if ((q4.z != cv) && (wb < wmin || !any)) { wmin = wb; umin = c0 + s*4 + 2; any = true; }
                    wb = __float_as_uint(w4.w);
                    if ((q4.w != cv) && (wb < wmin || !any)) { wmin = wb; umin = c0 + s*4 + 3; any = true; }
                }
                if (any) {
                    unsigned uv = (unsigned)v;
                    unsigned lo = (umin < uv) ? ((umin << 9) | uv) : ((uv << 9) | umin);
                    atomicMin(&best[cv], ((ull)wmin << 32) | (ull)lo);
                }
            }
        }
        __syncthreads();                           // best final

        // ================= merge: R3 verbatim =================
        // hook
        ull he = INF64; unsigned hp = 0, hlo = 0;
        if (tid < NV) {
            unsigned t = (unsigned)tid;
            he = best[t];
            hp = t;
            if (he != INF64) {
                hlo = (unsigned)he & 0x3FFFFu;
                unsigned ci = comp[hlo >> 9], cj = comp[hlo & 511u];
                hp = (ci == t) ? cj : ci;
            }
            parent[t] = hp;
        }
        __syncthreads();

        // break 2-cycles
        if (tid < NV) {
            unsigned t = (unsigned)tid, p = parent[t];
            if (p != t && parent[p] == t && t < p) parent[t] = t;
        }
        __syncthreads();

        // accept (dedup mutual picks via unique key)
        if (tid < NV && he != INF64) {
            bool dup = (best[hp] == he) && (hp < (unsigned)tid);
            if (!dup) {
                float a = __uint_as_float((unsigned)(he >> 32)); // Dm[i][j]
                float b = Do[hlo];                 // (i<<9)|j == i*512+j
                float d = a - b;
                contrib += d * d;
                atomicAdd(&accTot, 1);
            }
        }

        // pointer jumping (9 doublings; races only accelerate)
        for (int jt = 0; jt < 9; ++jt) {
            __syncthreads();
            if (tid < NV) parent[tid] = parent[parent[tid]];
        }
        __syncthreads();

        // relabel
        if (tid < NV) comp[tid] = parent[comp[tid]];
        __syncthreads();

        if (accTot == NV - 1) break;               // uniform post-barrier
    }

    // ---- deterministic reduction: wave butterfly, then fixed-order sum
#pragma unroll
    for (int off = 32; off >= 1; off >>= 1) contrib += __shfl_xor(contrib, off);
    if (lane == 0) red[wid] = contrib;
    __syncthreads();
    if (tid == 0) {
        float s = 0.f;
#pragma unroll
        for (int w = 0; w < 16; ++w) s += red[w];
        partial[blk] = s;
    }
}

__global__ void final_add(const float* __restrict__ partial, float* __restrict__ out) {
    out[0] = partial[0] + partial[1];
}

} // namespace

extern "C" void kernel_launch(void* const* d_in, const int* in_sizes, int n_in,
                              void* d_out, int out_size, void* d_ws, size_t ws_size,
                              hipStream_t stream) {
    const float* d1 = (const float*)d_in[0];
    const float* d2 = (const float*)d_in[1];
    float* out = (float*)d_out;
    float* ws = (float*)d_ws;

    boruvka_loss<<<2, 1024, 0, stream>>>(d1, d2, ws); // writes ws[0], ws[1]
    final_add<<<1, 1, 0, stream>>>(ws, out);
}